// Round 18
// baseline (416.408 us; speedup 1.0000x reference)
//
#include <hip/hip_runtime.h>
#include <hip/hip_bf16.h>
#include <hip/hip_fp8.h>

typedef __attribute__((ext_vector_type(4))) float  fx4;
typedef __attribute__((ext_vector_type(4))) int    ix4;
typedef __attribute__((ext_vector_type(8))) int    ix8;

#define ROWS 8192   // B*S
#define HID  1024
#define MEMN 8192

// global_load_lds, 16B per lane; LDS dest = wave-uniform base + lane*16
#define GLDS(gp, lp) __builtin_amdgcn_global_load_lds( \
    (const __attribute__((address_space(1))) void*)(gp), \
    (__attribute__((address_space(3))) void*)(lp), 16, 0, 0)

#define MEMFENCE asm volatile("" ::: "memory")

__device__ __forceinline__ unsigned char f2q(float f) {
    __hip_fp8_e4m3 q(f);
    return (unsigned char)q.__x;
}
__device__ __forceinline__ float q2f(unsigned char b) {
    __hip_fp8_e4m3 q;
    q.__x = (__hip_fp8_storage_t)b;
    return (float)q;
}

// ---------------------------------------------------------------------------
// fp32 -> fp8 e4m3 elementwise convert (16 elems/thread), value *= premul.
// ---------------------------------------------------------------------------
__global__ __launch_bounds__(256)
void f32_to_fp8_vec(const float* __restrict__ in,
                    unsigned char* __restrict__ out, float premul)
{
    const size_t i = ((size_t)blockIdx.x * 256 + threadIdx.x) * 16;
    unsigned char b[16];
#pragma unroll
    for (int q = 0; q < 4; ++q) {
        fx4 v = *(const fx4*)(in + i + q * 4);
        b[q * 4 + 0] = f2q(v[0] * premul);
        b[q * 4 + 1] = f2q(v[1] * premul);
        b[q * 4 + 2] = f2q(v[2] * premul);
        b[q * 4 + 3] = f2q(v[3] * premul);
    }
    *(ix4*)(out + i) = *(ix4*)b;
}

// ---------------------------------------------------------------------------
// fp32 [R][C] -> fp8 [C][R] transpose (64x64 tiles via LDS).
// scale != nullptr: multiply element (r,c) by scale[r]; then by premul.
// ---------------------------------------------------------------------------
__global__ __launch_bounds__(256)
void transpose_f32_to_fp8(const float* __restrict__ in,
                          unsigned char* __restrict__ out,
                          const float* __restrict__ scale, float premul,
                          int R, int C)
{
    __shared__ float t[64][65];
    const int tid = threadIdx.x;
    const int r0 = blockIdx.y * 64;
    const int c0 = blockIdx.x * 64;
    const int lr = tid >> 4;
    const int lc = (tid & 15) * 4;
#pragma unroll
    for (int p = 0; p < 4; ++p) {
        const int rr = p * 16 + lr;
        const fx4 v = *(const fx4*)(in + (size_t)(r0 + rr) * C + c0 + lc);
        t[rr][lc + 0] = v[0]; t[rr][lc + 1] = v[1];
        t[rr][lc + 2] = v[2]; t[rr][lc + 3] = v[3];
    }
    __syncthreads();
    const int oc = tid >> 2;
    const int ob = (tid & 3) * 16;
    unsigned char b[16];
#pragma unroll
    for (int j = 0; j < 16; ++j) {
        float v = t[ob + j][oc];
        if (scale) v *= scale[r0 + ob + j];
        b[j] = f2q(v * premul);
    }
    *(ix4*)(out + (size_t)(c0 + oc) * R + r0 + ob) = *(ix4*)b;
}

// ---------------------------------------------------------------------------
// colsum_partial_q: part[chunk][s] = sum over 128 rows of fp8 W[m][s].
// ---------------------------------------------------------------------------
__global__ __launch_bounds__(256)
void colsum_partial_q(const unsigned char* __restrict__ W,
                      float* __restrict__ part)
{
    const int s0 = blockIdx.x * 4096 + threadIdx.x * 16;
    const int m0 = blockIdx.y * 128;
    float a[16];
#pragma unroll
    for (int j = 0; j < 16; ++j) a[j] = 0.f;
    for (int r = 0; r < 128; ++r) {
        ix4 u = *(const ix4*)(W + (size_t)(m0 + r) * MEMN + s0);
        const unsigned char* ub = (const unsigned char*)&u;
#pragma unroll
        for (int j = 0; j < 16; ++j) a[j] += q2f(ub[j]);
    }
#pragma unroll
    for (int q = 0; q < 4; ++q)
        *(fx4*)(part + (size_t)blockIdx.y * MEMN + s0 + q * 4) =
            *(fx4*)(a + q * 4);
}

// ---------------------------------------------------------------------------
// colsum_finalize: invc[s] = 1 / sum_c part[c][s].
// ---------------------------------------------------------------------------
__global__ __launch_bounds__(256)
void colsum_finalize(const float* __restrict__ part, float* __restrict__ invc)
{
    const int s = blockIdx.x * 256 + threadIdx.x;
    float t = 0.f;
#pragma unroll 8
    for (int c = 0; c < 64; ++c) t += part[(size_t)c * MEMN + s];
    invc[s] = 1.0f / t;
}

// ---------------------------------------------------------------------------
// gemm8q: MX-fp8 NT GEMM (all four GEMMs). 128x256 tile, BK=128, 512 thr =
// 8 waves (2Mx4N), wave tile 64x64. Ring-3 LDS (144 KiB); counted-vmcnt
// ledger (L=6).  r17 changes vs r16:
//  (1) ROTATED granule swizzle: LDS pos p of row r holds k-granule
//      rot_inv(p ^ (r&7)), rot(k) = (k>>1)|((k&1)<<2).  A fragment's two
//      16B reads land at g0 = fh^(r&7) and g0^4 (64B apart, different bank
//      halves) instead of adjacent granules -> targets the measured 8.4M
//      SQ_LDS_BANK_CONFLICT (4 per ds_read_b128).
//  (2) L2 rasterization: column-groups of G=min(8,nBN) sweep all rows
//      before advancing (B sub-panel 2MB fits per-XCD L2).
// Modes: 2 = f32 c*oscale+add; 3 = fp8 exp(c*cscale+bias[col]);
//        4 = fp8 exp(c*cscale+bias[row]); 5 = f32 c/rowsum (ones-MFMA).
// ---------------------------------------------------------------------------
template <int MODE>
__global__ __launch_bounds__(512)
void gemm8q(const unsigned char* __restrict__ A,
            const unsigned char* __restrict__ B,
            const float* __restrict__ bias, const float* __restrict__ add,
            void* __restrict__ out,
            int N, int K, int nBN, float oscale, float cscale)
{
    constexpr int ASZ = 128 * 128;    // 16 KiB per A slot
    constexpr int BSZ = 256 * 128;    // 32 KiB per B slot
    __shared__ __align__(16) char smem[3 * (ASZ + BSZ)];   // 144 KiB
    char* const As = smem;
    char* const Bs = smem + 3 * ASZ;

    const int tid = threadIdx.x;
    const int wid = tid >> 6;
    const int ln  = tid & 63;
    const int fl  = ln & 15;
    const int fh  = ln >> 4;
    const int wr  = wid >> 2;          // 0..1 -> rows wr*64
    const int wc  = wid & 3;           // 0..3 -> cols wc*64

    // XCD swizzle + L2-friendly rasterization (col-groups of G sweep rows)
    const int nwg = gridDim.x;
    const int bid = blockIdx.x;
    const int wg  = (bid & 7) * (nwg >> 3) + (bid >> 3);
    const int G   = (nBN >= 8) ? 8 : nBN;
    const int nBM = nwg / nBN;
    const int grp = nBM * G;
    const int cg  = wg / grp;
    const int rem = wg % grp;
    const int tm  = (rem / G) * 128;
    const int tn  = (cg * G + rem % G) * 256;
    const int NT  = K >> 7;            // K/128

    // staging: thread t -> row 64*round + (t>>3), LDS granule t&7.
    // source k-granule = rot_inv((t&7) ^ ((t>>3)&7))
    const int trow = tid >> 3;
    const int qq   = (tid & 7) ^ ((tid >> 3) & 7);
    const int tsrc = (((qq & 3) << 1) | (qq >> 2)) * 16;
    const unsigned char* Ag[2];
    const unsigned char* Bg[4];
#pragma unroll
    for (int r = 0; r < 2; ++r)
        Ag[r] = A + (size_t)(tm + 64 * r + trow) * K + tsrc;
#pragma unroll
    for (int r = 0; r < 4; ++r)
        Bg[r] = B + (size_t)(tn + 64 * r + trow) * K + tsrc;

    auto stage = [&](int t) {
        const int s = t % 3;
        const size_t ko = (size_t)t * 128;
#pragma unroll
        for (int r = 0; r < 2; ++r)
            GLDS(Ag[r] + ko, As + s * ASZ + r * 8192 + wid * 1024);
#pragma unroll
        for (int r = 0; r < 4; ++r)
            GLDS(Bg[r] + ko, Bs + s * BSZ + r * 8192 + wid * 1024);
    };

    fx4 acc[4][4] = {};
    fx4 accs[4] = {};                  // MODE 5: row sums via ones-MFMA
    ix8 ones;
#pragma unroll
    for (int j = 0; j < 8; ++j) ones[j] = 0x38383838;   // fp8 e4m3 1.0 x4

    stage(0);
    stage(1);

    for (int t = 0; t < NT; ++t) {
        if (t == NT - 1) asm volatile("s_waitcnt vmcnt(0)" ::: "memory");
        else             asm volatile("s_waitcnt vmcnt(6)" ::: "memory");
        __builtin_amdgcn_s_barrier();
        MEMFENCE;
        if (t + 2 < NT) stage(t + 2);

        const char* Ab = As + (t % 3) * ASZ;
        const char* Bb = Bs + (t % 3) * BSZ;

        ix8 fa[4], fb[4];
#pragma unroll
        for (int mi = 0; mi < 4; ++mi) {
            const int r  = wr * 64 + mi * 16 + fl;
            const int g0 = fh ^ (r & 7);           // rot(2fh)   ^ (r&7)
            const int g1 = g0 ^ 4;                 // rot(2fh+1) ^ (r&7)
            ix4 lo = *(const ix4*)(Ab + r * 128 + g0 * 16);
            ix4 hi = *(const ix4*)(Ab + r * 128 + g1 * 16);
            fa[mi][0] = lo[0]; fa[mi][1] = lo[1]; fa[mi][2] = lo[2]; fa[mi][3] = lo[3];
            fa[mi][4] = hi[0]; fa[mi][5] = hi[1]; fa[mi][6] = hi[2]; fa[mi][7] = hi[3];
        }
#pragma unroll
        for (int ni = 0; ni < 4; ++ni) {
            const int c  = wc * 64 + ni * 16 + fl;
            const int g0 = fh ^ (c & 7);
            const int g1 = g0 ^ 4;
            ix4 lo = *(const ix4*)(Bb + c * 128 + g0 * 16);
            ix4 hi = *(const ix4*)(Bb + c * 128 + g1 * 16);
            fb[ni][0] = lo[0]; fb[ni][1] = lo[1]; fb[ni][2] = lo[2]; fb[ni][3] = lo[3];
            fb[ni][4] = hi[0]; fb[ni][5] = hi[1]; fb[ni][6] = hi[2]; fb[ni][7] = hi[3];
        }
        __builtin_amdgcn_s_setprio(1);
#pragma unroll
        for (int mi = 0; mi < 4; ++mi)
#pragma unroll
            for (int ni = 0; ni < 4; ++ni)
                acc[mi][ni] = __builtin_amdgcn_mfma_scale_f32_16x16x128_f8f6f4(
                    fa[mi], fb[ni], acc[mi][ni], 0, 0, 0, 127, 0, 127);
        if constexpr (MODE == 5) {
#pragma unroll
            for (int mi = 0; mi < 4; ++mi)
                accs[mi] = __builtin_amdgcn_mfma_scale_f32_16x16x128_f8f6f4(
                    fa[mi], ones, accs[mi], 0, 0, 0, 127, 0, 127);
        }
        __builtin_amdgcn_s_setprio(0);
    }

    // epilogue: C/D layout col = lane&15, row = (lane>>4)*4 + reg
#pragma unroll
    for (int mi = 0; mi < 4; ++mi) {
#pragma unroll
        for (int ni = 0; ni < 4; ++ni) {
            const int gr0 = tm + wr * 64 + mi * 16 + fh * 4;
            const int gc  = tn + wc * 64 + ni * 16 + fl;
            fx4 c = acc[mi][ni];
            if constexpr (MODE == 2) {
                float* O = (float*)out;
#pragma unroll
                for (int j = 0; j < 4; ++j) {
                    const size_t idx = (size_t)(gr0 + j) * N + gc;
                    O[idx] = c[j] * oscale + add[idx];
                }
            } else if constexpr (MODE == 3) {
                unsigned char* O = (unsigned char*)out;
                const float bv = bias[gc];
#pragma unroll
                for (int j = 0; j < 4; ++j)
                    O[(size_t)(gr0 + j) * N + gc] =
                        f2q(__expf(c[j] * cscale + bv));
            } else if constexpr (MODE == 4) {
                unsigned char* O = (unsigned char*)out;
#pragma unroll
                for (int j = 0; j < 4; ++j)
                    O[(size_t)(gr0 + j) * N + gc] =
                        f2q(__expf(c[j] * cscale + bias[gr0 + j]));
            } else {   // MODE 5: self-normalizing
                float* O = (float*)out;
#pragma unroll
                for (int j = 0; j < 4; ++j)
                    O[(size_t)(gr0 + j) * N + gc] = c[j] / accs[mi][j];
            }
        }
    }
}

// ---------------------------------------------------------------------------
// Orchestration — all-fp8 pipeline (layout unchanged from r16):
//   xq @ 0 (8MB) | slot1 @ 16MiB (rwq/wwq -> part+invc) | slot2 @ 32MiB
//   (memT fp8 -> xT*invc*8192 fp8) | Wq @ 48MiB (64MB)
// Weights quantized as 32*w (escape e4m3 subnormals); logits epilogue
// multiplies acc by cscale = 1/32 before exp.
// ---------------------------------------------------------------------------
extern "C" void kernel_launch(void* const* d_in, const int* in_sizes, int n_in,
                              void* d_out, int out_size, void* d_ws, size_t ws_size,
                              hipStream_t stream)
{
    const float* x       = (const float*)d_in[0];
    const float* memory  = (const float*)d_in[1];
    const float* read_w  = (const float*)d_in[2];
    const float* read_b  = (const float*)d_in[3];
    const float* write_w = (const float*)d_in[4];
    const float* write_b = (const float*)d_in[5];

    float* out_read = (float*)d_out;
    float* out_mem  = (float*)d_out + (size_t)MEMN * HID;

    char* p = (char*)d_ws;
    const size_t MiB = 1024 * 1024;
    unsigned char* xq    = (unsigned char*)(p + 0 * MiB);
    unsigned char* slot1 = (unsigned char*)(p + 16 * MiB);
    unsigned char* slot2 = (unsigned char*)(p + 32 * MiB);
    unsigned char* Wq    = (unsigned char*)(p + 48 * MiB);
    float*         part  = (float*)(p + 16 * MiB);     // after wwq dead
    float*         invc  = (float*)(p + 20 * MiB);

    // ---- read path ---------------------------------------------------------
    f32_to_fp8_vec<<<2048, 256, 0, stream>>>(x, xq, 1.0f);
    f32_to_fp8_vec<<<2048, 256, 0, stream>>>(read_w, slot1, 32.0f);
    transpose_f32_to_fp8<<<dim3(HID / 64, ROWS / 64), 256, 0, stream>>>(
        memory, slot2, nullptr, 1.0f, ROWS, HID);
    // Wq[s][m] = e4m3(exp((x.rw^T)/32*32 + rb))
    gemm8q<3><<<(ROWS / 128) * (MEMN / 256), 512, 0, stream>>>(
        xq, slot1, read_b, nullptr, Wq, MEMN, HID, MEMN / 256, 1.0f, 1.0f / 32.0f);
    // out_read[s][h] = (sum_m Wq[s,m] memT[h,m]) / (sum_m Wq[s,m])
    gemm8q<5><<<(ROWS / 128) * (HID / 256), 512, 0, stream>>>(
        Wq, slot2, nullptr, nullptr, out_read, HID, MEMN, HID / 256, 1.0f, 1.0f);

    // ---- write path --------------------------------------------------------
    f32_to_fp8_vec<<<2048, 256, 0, stream>>>(write_w, slot1, 32.0f);
    // Wq^T[m][s] = e4m3(exp((ww.x^T) + wb[m]))
    gemm8q<4><<<(MEMN / 128) * (ROWS / 256), 512, 0, stream>>>(
        slot1, xq, write_b, nullptr, Wq, ROWS, HID, ROWS / 256, 1.0f, 1.0f / 32.0f);
    colsum_partial_q<<<dim3(2, 64), 256, 0, stream>>>(Wq, part);
    colsum_finalize<<<32, 256, 0, stream>>>(part, invc);
    // xT[h][s] = e4m3(x[s][h] * invc[s] * 8192)
    transpose_f32_to_fp8<<<dim3(HID / 64, ROWS / 64), 256, 0, stream>>>(
        x, slot2, invc, 8192.0f, ROWS, HID);
    // out_mem[m][h] = memory[m,h] + (1/8192) * sum_s Wq^T[m,s] xT[h,s]
    gemm8q<2><<<(MEMN / 128) * (HID / 256), 512, 0, stream>>>(
        Wq, slot2, nullptr, memory, out_mem, HID, ROWS, HID / 256,
        1.0f / 8192.0f, 1.0f);
}